// Round 4
// baseline (292.001 us; speedup 1.0000x reference)
//
#include <hip/hip_runtime.h>
#include <hip/hip_bf16.h>
#include <cstddef>

// ---------------------------------------------------------------------------
// 3-layer MPNN, N=50000, E=800000, D=128, OUT=32.
// R16 = R15 resubmit (container failed twice; no counters). Only change:
// __launch_bounds__(512,4) -> (512) -- the forced 128-VGPR cap was the one
// limit-pushing construct; everything else audited in-bounds/uniform.
// Design (R15): aggregate+GEMM(+out-GEMM) fused per layer. R13/R14 showed
// fused_gemm pinned at ~39us = 985 GB/s (Little's-law MLP wall: ~1.1KB/CU
// in flight). Fix: never materialize g/h3 in HBM. Block(512)=8 waves owns
// 32 rows:
//  phase0: T14 issue-early H-tile load (pre-swizzled source);
//  phase1: each wave aggregates 4 nodes -> swizzled LDS G-tile (edge
//          gathers give natural MLP; memory stays saturated);
//  phase2: barrier; wave (gblk,ctp) MFMAs 16 rows x 32 cols, W in regs,
//          A-frags from LDS (XOR swizzle, 2-way conflicts = free);
//  layer3: h3 -> LDS, fold output GEMM (h3 never hits HBM).
// Binning/CSR unchanged.  CSR entry: (src:u16 | w:bf16<<16).
// ---------------------------------------------------------------------------

typedef __attribute__((ext_vector_type(8))) short short8;
typedef __attribute__((ext_vector_type(4))) float f32x4;
typedef unsigned short ushort_t;
typedef unsigned int uint_t;

#define BSH 8               // bucket shift: 256 nodes per bucket
#define BSZ 256             // nodes per bucket
#define CAPB 6144           // staged entries per bucket (mean 4096, >30 sigma)
#define TSTRIDE 16          // tails counter stride in ints (64B line each)
#define EPB 2048            // edges per bin block

__device__ inline ushort_t f2bf(float f) {  // round-to-nearest-even
    uint_t u = __float_as_uint(f);
    uint_t r = u + 0x7FFFu + ((u >> 16) & 1u);
    return (ushort_t)(r >> 16);
}
__device__ inline float bf_lo(uint_t u) { return __uint_as_float(u << 16); }
__device__ inline float bf_hi(uint_t u) { return __uint_as_float(u & 0xFFFF0000u); }
__device__ inline uint_t packbf(float a, float b) {
    return (uint_t)f2bf(a) | ((uint_t)f2bf(b) << 16);
}

// fast tanh: 1 - 2/(exp2(2*log2e*x)+1); saturates correctly at +-inf.
__device__ inline float fast_tanh(float x) {
    float e = __builtin_amdgcn_exp2f(x * 2.8853900817779268f);
    return 1.f - 2.f * __builtin_amdgcn_rcpf(e + 1.f);
}

// flag=1 -> int32 [2][E]; flag=0 -> int64 [2][E] (vectorized low-word read)
__device__ inline int get_dst(const int* __restrict__ ei, int e, int E, int f) {
    if (f) return ei[E + e];
    return ((const int2*)ei)[(size_t)E + e].x;
}
__device__ inline int get_src(const int* __restrict__ ei, int e, int E, int f) {
    if (f) return ei[e];
    return ((const int2*)ei)[e].x;
}

// ---------------------------------------------------------------------------
// Fused setup: zero tails+cursor | detect idx layout | swizzled bf16 weights
// | x -> bf16.
// wswz[l]: flat ((ct*8+ks)*64+lane)*8+j <- Wcat[(ct*16+(lane&15))][ks*32+
//   (lane>>4)*8+j]  (Wcat = [Wm | Wu], K=256)
// woswz:   flat ((ct*4+ks)*64+lane)*8+j <- Wout[...]  (K=128, ct<2)
// ---------------------------------------------------------------------------
struct SetupArgs {
    const float* Wm0; const float* Wu0;
    const float* Wm1; const float* Wu1;
    const float* Wm2; const float* Wu2;
    const float* Wout;
    const float* x; const int* ei;
    ushort_t* wswz;    // 3 * 32768
    ushort_t* woswz;   // 4096
    ushort_t* xb;      // N*128
    int* tails;        // NB*TSTRIDE + cursor (zeroed together)
    int* flag;
    int N, E, TI;
    int ZT, WB, XB;
};
__global__ __launch_bounds__(256) void setup_kernel(SetupArgs a) {
    int bx = blockIdx.x, t = threadIdx.x;
    if (bx < a.ZT) {
        int i = bx * 256 + t;
        if (i < a.TI) a.tails[i] = 0;
        return;
    }
    bx -= a.ZT;
    if (bx == 0) {
        __shared__ int any;
        if (t == 0) any = 0;
        __syncthreads();
        int n = a.E < 2048 ? a.E : 2048;
        for (int i = t; i < n; i += 256)
            if (a.ei[2 * i + 1] != 0) any = 1;
        __syncthreads();
        if (t == 0) a.flag[0] = any;
        return;
    }
    bx -= 1;
    if (bx < a.WB) {
        int i = bx * 256 + t;
        if (i < 3 * 32768) {
            int l = i >> 15, r2 = i & 32767;
            int ct = r2 >> 12, ks = (r2 >> 9) & 7, lane = (r2 >> 3) & 63, j = r2 & 7;
            int col = ct * 16 + (lane & 15);
            int k = ks * 32 + (lane >> 4) * 8 + j;
            const float* Wm = l == 0 ? a.Wm0 : (l == 1 ? a.Wm1 : a.Wm2);
            const float* Wu = l == 0 ? a.Wu0 : (l == 1 ? a.Wu1 : a.Wu2);
            float v = k < 128 ? Wm[col * 128 + k] : Wu[col * 128 + (k - 128)];
            a.wswz[(size_t)l * 32768 + r2] = f2bf(v);
        } else if (i < 3 * 32768 + 4096) {
            int r2 = i - 3 * 32768;
            int ct = r2 >> 11, ks = (r2 >> 9) & 3, lane = (r2 >> 3) & 63, j = r2 & 7;
            int col = ct * 16 + (lane & 15);
            int k = ks * 32 + (lane >> 4) * 8 + j;
            a.woswz[r2] = f2bf(a.Wout[col * 128 + k]);
        }
        return;
    }
    bx -= a.WB;
    {
        int j = bx * 256 + t;
        if (j < a.N * 32) {
            float4 v = *(const float4*)(a.x + (size_t)j * 4);
            uint2 o;
            o.x = packbf(v.x, v.y);
            o.y = packbf(v.z, v.w);
            *(uint2*)(a.xb + (size_t)j * 4) = o;
        }
    }
}

// ---------------------------------------------------------------------------
// Phase A: LDS multi-split binning (one global atomic per (block,bucket)).
// ---------------------------------------------------------------------------
__global__ __launch_bounds__(256) void bin_kernel(
    const int* __restrict__ ei, const float* __restrict__ ew,
    const int* __restrict__ flag, int* __restrict__ tails,
    uint2* __restrict__ staged, int E, int NB) {
    __shared__ uint2 ent[EPB];           // 16 KB
    __shared__ int cnt[256], cur[256], runbase[256];
    const int tid = threadIdx.x;
    const int e0 = blockIdx.x * EPB;
    const int nE = (E - e0) < EPB ? (E - e0) : EPB;
    const int f = flag[0];
    cnt[tid] = 0;
    cur[tid] = 0;
    __syncthreads();
    for (int i = tid; i < nE; i += 256) {
        int e = e0 + i;
        int s = get_src(ei, e, E, f);
        int d = get_dst(ei, e, E, f);
        uint2 v;
        v.x = (uint_t)s | ((uint_t)f2bf(ew[e]) << 16);
        v.y = (uint_t)d;
        ent[i] = v;
        atomicAdd(&cnt[d >> BSH], 1);    // LDS atomic
    }
    __syncthreads();
    if (tid < NB) {
        int c = cnt[tid];
        runbase[tid] = c ? atomicAdd(&tails[tid * TSTRIDE], c) : 0;
    }
    __syncthreads();
    for (int i = tid; i < nE; i += 256) {
        uint2 v = ent[i];
        int d = (int)v.y;
        int b = d >> BSH;
        int lp = atomicAdd(&cur[b], 1);  // LDS atomic
        int gp = runbase[b] + lp;
        if (gp < CAPB) {
            uint2 o;
            o.x = v.x;
            o.y = (uint_t)(d & (BSZ - 1));
            staged[(size_t)b * CAPB + gp] = o;
        }
    }
}

// ---------------------------------------------------------------------------
// Phase B: one block per bucket -> contiguous CSR region + rowdeg{beg,end}.
// ---------------------------------------------------------------------------
__global__ __launch_bounds__(256) void place_kernel(
    const uint2* __restrict__ staged, const int* __restrict__ tails,
    int* __restrict__ cursor, uint_t* __restrict__ csr,
    int2* __restrict__ rowdeg, int N) {
    __shared__ int cnt[256], cur[256], excl[256], sm[256];
    __shared__ int baseSh;
    __shared__ uint_t outb[CAPB];        // 24 KB
    const int b = blockIdx.x, tid = threadIdx.x;
    const int node0 = b << BSH;
    int tot = tails[b * TSTRIDE];
    tot = tot < CAPB ? tot : CAPB;
    cnt[tid] = 0;
    __syncthreads();
    const uint2* sp = staged + ((size_t)b * CAPB);
    for (int i = tid; i < tot; i += 256) atomicAdd(&cnt[sp[i].y], 1);
    __syncthreads();
    int c0 = cnt[tid];
    sm[tid] = c0;
    __syncthreads();
    for (int o = 1; o < 256; o <<= 1) {
        int v = tid >= o ? sm[tid - o] : 0;
        __syncthreads();
        sm[tid] += v;
        __syncthreads();
    }
    if (tid == 255) baseSh = atomicAdd(cursor, sm[255]);
    excl[tid] = sm[tid] - c0;
    cur[tid] = 0;
    __syncthreads();
    const int base = baseSh;
    for (int i = tid; i < tot; i += 256) {
        uint2 e = sp[i];
        int pos = excl[e.y] + atomicAdd(&cur[e.y], 1);
        outb[pos] = e.x;
    }
    __syncthreads();
    for (int i = tid; i < tot; i += 256) csr[base + i] = outb[i];
    if (node0 + tid < N) {
        int2 be;
        be.x = base + excl[tid];
        be.y = base + excl[tid] + c0;
        rowdeg[node0 + tid] = be;
    }
}

// ---------------------------------------------------------------------------
// Fused layer: block(512)=8 waves owns 32 rows.
//   phase1: wave wv aggregates nodes R0+wv*4..+3 into swizzled LDS Gt;
//           H-tile staged issue-early/write-late into swizzled LDS Ht.
//   phase2: wave (gblk=wv&1, ctp=wv>>1) computes rows gblk*16.., cols
//           ctp*32.. : h' = tanh([Gt|Ht] @ Wswz + bu).
//   WITH_OUT: h3 -> Gt (swizzled), then waves 0-3 do out = h3 @ Woswz + bout.
// LDS swizzle (ushort units): 8-elem block b of row r lives at block
// b ^ (r&7) -> ds_read_b128 A-frags are 2-way conflicts (free, m136).
// ---------------------------------------------------------------------------
template <int WITH_OUT>
__global__ __launch_bounds__(512) void fused_layer(
    const uint_t* __restrict__ csr, const int2* __restrict__ rowdeg,
    const ushort_t* __restrict__ h, const ushort_t* __restrict__ Wswz,
    const float* __restrict__ bias, ushort_t* __restrict__ Hout,
    const ushort_t* __restrict__ Woswz, const float* __restrict__ bout,
    float* __restrict__ Cout, int N) {
    __shared__ ushort_t Gt[32 * 128];    // 8 KB, swizzled
    __shared__ ushort_t Ht[32 * 128];    // 8 KB, swizzled
    const int tid = threadIdx.x;
    const int lane = tid & 63;
    const int wv = tid >> 6;
    const int R0 = blockIdx.x * 32;
    const int slot = lane >> 3, f8 = lane & 7;

    // -- T14 issue-early: H-tile load with pre-swizzled source ------------
    const int pp = tid * 16;                  // LDS byte pos (512*16B = 8KB)
    const int srow = pp >> 8;                 // local row 0..31
    const int sx = (pp & 255) ^ ((srow & 7) << 4);
    uint4 hst = *(const uint4*)(h + (size_t)(R0 + srow) * 128 + (sx >> 1));

    // -- phase 1: aggregation of 4 nodes per wave -------------------------
    int2 be[4];
#pragma unroll
    for (int i = 0; i < 4; ++i) {
        int nd = R0 + wv * 4 + i;
        if (nd < N) be[i] = rowdeg[nd];
        else { be[i].x = 0; be[i].y = 0; }
    }
#pragma unroll
    for (int i = 0; i < 4; ++i) {
        const int lr = wv * 4 + i;
        float s[16];
#pragma unroll
        for (int k = 0; k < 16; ++k) s[k] = 0.f;
        int j = be[i].x + slot;
        const int end = be[i].y;
        for (; j + 8 < end; j += 16) {
            uint_t p0 = csr[j];
            uint_t p1 = csr[j + 8];
            float w0 = bf_hi(p0), w1 = bf_hi(p1);
            const ushort_t* r0 = h + (size_t)(p0 & 0xFFFFu) * 128 + f8 * 16;
            const ushort_t* r1 = h + (size_t)(p1 & 0xFFFFu) * 128 + f8 * 16;
            uint4 v0 = *(const uint4*)(r0);
            uint4 v1 = *(const uint4*)(r0 + 8);
            uint4 u0 = *(const uint4*)(r1);
            uint4 u1 = *(const uint4*)(r1 + 8);
            s[0] += w0 * bf_lo(v0.x);  s[1] += w0 * bf_hi(v0.x);
            s[2] += w0 * bf_lo(v0.y);  s[3] += w0 * bf_hi(v0.y);
            s[4] += w0 * bf_lo(v0.z);  s[5] += w0 * bf_hi(v0.z);
            s[6] += w0 * bf_lo(v0.w);  s[7] += w0 * bf_hi(v0.w);
            s[8] += w0 * bf_lo(v1.x);  s[9] += w0 * bf_hi(v1.x);
            s[10] += w0 * bf_lo(v1.y); s[11] += w0 * bf_hi(v1.y);
            s[12] += w0 * bf_lo(v1.z); s[13] += w0 * bf_hi(v1.z);
            s[14] += w0 * bf_lo(v1.w); s[15] += w0 * bf_hi(v1.w);
            s[0] += w1 * bf_lo(u0.x);  s[1] += w1 * bf_hi(u0.x);
            s[2] += w1 * bf_lo(u0.y);  s[3] += w1 * bf_hi(u0.y);
            s[4] += w1 * bf_lo(u0.z);  s[5] += w1 * bf_hi(u0.z);
            s[6] += w1 * bf_lo(u0.w);  s[7] += w1 * bf_hi(u0.w);
            s[8] += w1 * bf_lo(u1.x);  s[9] += w1 * bf_hi(u1.x);
            s[10] += w1 * bf_lo(u1.y); s[11] += w1 * bf_hi(u1.y);
            s[12] += w1 * bf_lo(u1.z); s[13] += w1 * bf_hi(u1.z);
            s[14] += w1 * bf_lo(u1.w); s[15] += w1 * bf_hi(u1.w);
        }
        if (j < end) {
            uint_t p = csr[j];
            float w = bf_hi(p);
            const ushort_t* row = h + (size_t)(p & 0xFFFFu) * 128 + f8 * 16;
            uint4 v0 = *(const uint4*)(row);
            uint4 v1 = *(const uint4*)(row + 8);
            s[0] += w * bf_lo(v0.x);  s[1] += w * bf_hi(v0.x);
            s[2] += w * bf_lo(v0.y);  s[3] += w * bf_hi(v0.y);
            s[4] += w * bf_lo(v0.z);  s[5] += w * bf_hi(v0.z);
            s[6] += w * bf_lo(v0.w);  s[7] += w * bf_hi(v0.w);
            s[8] += w * bf_lo(v1.x);  s[9] += w * bf_hi(v1.x);
            s[10] += w * bf_lo(v1.y); s[11] += w * bf_hi(v1.y);
            s[12] += w * bf_lo(v1.z); s[13] += w * bf_hi(v1.z);
            s[14] += w * bf_lo(v1.w); s[15] += w * bf_hi(v1.w);
        }
#pragma unroll
        for (int k = 0; k < 16; ++k) s[k] += __shfl_xor(s[k], 8, 64);
#pragma unroll
        for (int k = 0; k < 16; ++k) s[k] += __shfl_xor(s[k], 16, 64);
#pragma unroll
        for (int k = 0; k < 16; ++k) s[k] += __shfl_xor(s[k], 32, 64);
        if (slot == 0) {
            uint4 o0, o1;
            o0.x = packbf(s[0], s[1]);   o0.y = packbf(s[2], s[3]);
            o0.z = packbf(s[4], s[5]);   o0.w = packbf(s[6], s[7]);
            o1.x = packbf(s[8], s[9]);   o1.y = packbf(s[10], s[11]);
            o1.z = packbf(s[12], s[13]); o1.w = packbf(s[14], s[15]);
            const int sw = (lr & 7) << 3;
            *(uint4*)(Gt + lr * 128 + ((f8 * 16) ^ sw)) = o0;
            *(uint4*)(Gt + lr * 128 + ((f8 * 16 + 8) ^ sw)) = o1;
        }
    }
    // -- write-late H tile ------------------------------------------------
    *(uint4*)((char*)Ht + pp) = hst;
    __syncthreads();

    // -- phase 2: MFMA. wave task: gblk = wv&1 (16 rows), ctp = wv>>1 -----
    const int gblk = wv & 1, ctp = wv >> 1;
    const int m = lane & 15, kg = lane >> 4;
    const int lrow = gblk * 16 + m;
    const int lsw = (lrow & 7) << 3;
    const int colL = lane & 15, rq = lane >> 4;

    short8 b0[8], b1[8];
#pragma unroll
    for (int ksp = 0; ksp < 8; ++ksp) {
        b0[ksp] = *(const short8*)(Wswz + (((2 * ctp) * 8 + ksp) * 64 + lane) * 8);
        b1[ksp] = *(const short8*)(Wswz + (((2 * ctp + 1) * 8 + ksp) * 64 + lane) * 8);
    }
    const float bv0 = bias[(2 * ctp) * 16 + colL];
    const float bv1 = bias[(2 * ctp + 1) * 16 + colL];

    f32x4 acc0 = (f32x4){0.f, 0.f, 0.f, 0.f};
    f32x4 acc1 = (f32x4){0.f, 0.f, 0.f, 0.f};
#pragma unroll
    for (int ksp = 0; ksp < 8; ++ksp) {
        const ushort_t* tp = (ksp < 4) ? Gt : Ht;
        short8 av = *(const short8*)(tp + lrow * 128 + (((ksp & 3) * 32 + kg * 8) ^ lsw));
        acc0 = __builtin_amdgcn_mfma_f32_16x16x32_bf16(av, b0[ksp], acc0, 0, 0, 0);
        acc1 = __builtin_amdgcn_mfma_f32_16x16x32_bf16(av, b1[ksp], acc1, 0, 0, 0);
    }
    float v0[4], v1[4];
#pragma unroll
    for (int reg = 0; reg < 4; ++reg) {
        v0[reg] = fast_tanh(acc0[reg] + bv0);
        v1[reg] = fast_tanh(acc1[reg] + bv1);
    }

    if (WITH_OUT == 0) {
#pragma unroll
        for (int reg = 0; reg < 4; ++reg) {
            int gr = R0 + gblk * 16 + rq * 4 + reg;
            if (gr < N) {
                Hout[(size_t)gr * 128 + (2 * ctp) * 16 + colL] = f2bf(v0[reg]);
                Hout[(size_t)gr * 128 + (2 * ctp + 1) * 16 + colL] = f2bf(v1[reg]);
            }
        }
    } else {
        // h3 -> Gt (swizzled), then out = h3 @ Woswz + bout
        __syncthreads();   // all A-reads of Gt done before overwrite
#pragma unroll
        for (int reg = 0; reg < 4; ++reg) {
            int lr3 = gblk * 16 + rq * 4 + reg;
            int sw3 = (lr3 & 7) << 3;
            Gt[lr3 * 128 + (((2 * ctp) * 16 + colL) ^ sw3)] = f2bf(v0[reg]);
            Gt[lr3 * 128 + (((2 * ctp + 1) * 16 + colL) ^ sw3)] = f2bf(v1[reg]);
        }
        __syncthreads();
        if (wv < 4) {
            const int og = wv & 1, oc = wv >> 1;      // og: row grp, oc: col tile
            const int orow = og * 16 + m;
            const int osw = (orow & 7) << 3;
            short8 ob[4];
#pragma unroll
            for (int ks = 0; ks < 4; ++ks)
                ob[ks] = *(const short8*)(Woswz + ((oc * 4 + ks) * 64 + lane) * 8);
            f32x4 oacc = (f32x4){0.f, 0.f, 0.f, 0.f};
#pragma unroll
            for (int ks = 0; ks < 4; ++ks) {
                short8 av = *(const short8*)(Gt + orow * 128 + ((ks * 32 + kg * 8) ^ osw));
                oacc = __builtin_amdgcn_mfma_f32_16x16x32_bf16(av, ob[ks], oacc, 0, 0, 0);
            }
            const float obv = bout[oc * 16 + colL];
#pragma unroll
            for (int reg = 0; reg < 4; ++reg) {
                int gr = R0 + og * 16 + rq * 4 + reg;
                if (gr < N) Cout[(size_t)gr * 32 + oc * 16 + colL] = oacc[reg] + obv;
            }
        }
    }
}

extern "C" void kernel_launch(void* const* d_in, const int* in_sizes, int n_in,
                              void* d_out, int out_size, void* d_ws, size_t ws_size,
                              hipStream_t stream) {
    const float* x   = (const float*)d_in[0];
    const int* ei    = (const int*)d_in[1];
    const float* ew  = (const float*)d_in[2];
    const float* Wm[3] = {(const float*)d_in[3], (const float*)d_in[6], (const float*)d_in[9]};
    const float* Wu[3] = {(const float*)d_in[4], (const float*)d_in[7], (const float*)d_in[10]};
    const float* bu[3] = {(const float*)d_in[5], (const float*)d_in[8], (const float*)d_in[11]};
    const float* Wout = (const float*)d_in[12];
    const float* bout = (const float*)d_in[13];
    float* out = (float*)d_out;

    const int N = in_sizes[0] / 128;
    const int E = in_sizes[2];
    const size_t NPAD = 50048;
    const int NB = (N + BSZ - 1) / BSZ;  // 196 buckets
    const int TI = NB * TSTRIDE + 16;    // tails + cursor (zeroed together)

    ushort_t* xb    = (ushort_t*)d_ws;              // [NPAD,128] bf16
    ushort_t* hA    = xb + NPAD * 128;
    ushort_t* hB    = hA + NPAD * 128;
    ushort_t* gbuf  = hB + NPAD * 128;              // unused (kept for layout)
    ushort_t* wswz  = gbuf + NPAD * 128;            // 3*32768 bf16
    ushort_t* woswz = wswz + 3 * 32768;             // 4096 bf16
    int* flag       = (int*)(woswz + 4096);
    int* tails      = flag + 1;
    int* cursor     = tails + NB * TSTRIDE;         // inside zeroed TI range
    int* endp       = tails + TI;
    int2* rowdeg    = (int2*)(((uintptr_t)endp + 7) & ~(uintptr_t)7);
    uint2* staged   = (uint2*)(rowdeg + N + 8);
    uint_t* csr     = (uint_t*)(staged + (size_t)NB * CAPB);
    (void)ws_size;

    const int ZT = (TI + 255) / 256;
    const int WB = (3 * 32768 + 4096 + 255) / 256;  // 400
    const int XB = (N * 32 + 255) / 256;            // 6250
    const int gB = (E + EPB - 1) / EPB;             // 391
    const int gF = (N + 31) / 32;                   // 1563

    SetupArgs sa;
    sa.Wm0 = Wm[0]; sa.Wu0 = Wu[0];
    sa.Wm1 = Wm[1]; sa.Wu1 = Wu[1];
    sa.Wm2 = Wm[2]; sa.Wu2 = Wu[2];
    sa.Wout = Wout; sa.x = x; sa.ei = ei;
    sa.wswz = wswz; sa.woswz = woswz; sa.xb = xb;
    sa.tails = tails; sa.flag = flag;
    sa.N = N; sa.E = E; sa.TI = TI;
    sa.ZT = ZT; sa.WB = WB; sa.XB = XB;
    setup_kernel<<<ZT + 1 + WB + XB, 256, 0, stream>>>(sa);

    bin_kernel<<<gB, 256, 0, stream>>>(ei, ew, flag, tails, staged, E, NB);
    place_kernel<<<NB, 256, 0, stream>>>(staged, tails, cursor, csr, rowdeg, N);

    fused_layer<0><<<gF, 512, 0, stream>>>(csr, rowdeg, xb, wswz, bu[0], hA,
                                           nullptr, nullptr, nullptr, N);
    fused_layer<0><<<gF, 512, 0, stream>>>(csr, rowdeg, hA, wswz + 32768, bu[1], hB,
                                           nullptr, nullptr, nullptr, N);
    fused_layer<1><<<gF, 512, 0, stream>>>(csr, rowdeg, hB, wswz + 2 * 32768, bu[2],
                                           nullptr, woswz, bout, out, N);
}

// Round 5
// 258.442 us; speedup vs baseline: 1.1298x; 1.1298x over previous
//
#include <hip/hip_runtime.h>
#include <hip/hip_bf16.h>
#include <cstddef>

// ---------------------------------------------------------------------------
// 3-layer MPNN, N=50000, E=800000, D=128, OUT=32.
// R17: fix the gather-MLP collapse found in R16's counters (VGPR_Count=44:
// launch_bounds(512) made the allocator target 8 waves/SIMD and serialize
// the edge gather to ~1 chain in flight -> 59us latency-bound phase 1).
//  - fused_layer: block 256 = 4 waves / 16 rows; launch_bounds(256,4)
//    (<=128 VGPR). Phase 1 issues 4 edges/slot per batch (4 csr + 8 uint4
//    independent loads, clamp-to-last + w=0 padding; deg<=32 in one pass).
//  - phase 2: wave w = cols [32w,32w+32), W-frags in regs, A from swizzled
//    LDS Gt/Ht; layer 3 folds output GEMM via LDS h3 (waves 0-1).
//  - bin_kernel: LDS counting-sort by bucket before global scatter ->
//    stores coalesce into per-bucket runs.
// Binning/CSR semantics unchanged.  CSR entry: (src:u16 | w:bf16<<16).
// ---------------------------------------------------------------------------

typedef __attribute__((ext_vector_type(8))) short short8;
typedef __attribute__((ext_vector_type(4))) float f32x4;
typedef unsigned short ushort_t;
typedef unsigned int uint_t;

#define BSH 8               // bucket shift: 256 nodes per bucket
#define BSZ 256             // nodes per bucket
#define CAPB 6144           // staged entries per bucket (mean 4096, >30 sigma)
#define TSTRIDE 16          // tails counter stride in ints (64B line each)
#define EPB 2048            // edges per bin block

__device__ inline ushort_t f2bf(float f) {  // round-to-nearest-even
    uint_t u = __float_as_uint(f);
    uint_t r = u + 0x7FFFu + ((u >> 16) & 1u);
    return (ushort_t)(r >> 16);
}
__device__ inline float bf_lo(uint_t u) { return __uint_as_float(u << 16); }
__device__ inline float bf_hi(uint_t u) { return __uint_as_float(u & 0xFFFF0000u); }
__device__ inline uint_t packbf(float a, float b) {
    return (uint_t)f2bf(a) | ((uint_t)f2bf(b) << 16);
}

// fast tanh: 1 - 2/(exp2(2*log2e*x)+1); saturates correctly at +-inf.
__device__ inline float fast_tanh(float x) {
    float e = __builtin_amdgcn_exp2f(x * 2.8853900817779268f);
    return 1.f - 2.f * __builtin_amdgcn_rcpf(e + 1.f);
}

// flag=1 -> int32 [2][E]; flag=0 -> int64 [2][E] (vectorized low-word read)
__device__ inline int get_dst(const int* __restrict__ ei, int e, int E, int f) {
    if (f) return ei[E + e];
    return ((const int2*)ei)[(size_t)E + e].x;
}
__device__ inline int get_src(const int* __restrict__ ei, int e, int E, int f) {
    if (f) return ei[e];
    return ((const int2*)ei)[e].x;
}

// ---------------------------------------------------------------------------
// Fused setup: zero tails+cursor | detect idx layout | swizzled bf16 weights
// | x -> bf16.
// wswz[l]: flat ((ct*8+ks)*64+lane)*8+j <- Wcat[(ct*16+(lane&15))][ks*32+
//   (lane>>4)*8+j]  (Wcat = [Wm | Wu], K=256)
// woswz:   flat ((ct*4+ks)*64+lane)*8+j <- Wout[...]  (K=128, ct<2)
// ---------------------------------------------------------------------------
struct SetupArgs {
    const float* Wm0; const float* Wu0;
    const float* Wm1; const float* Wu1;
    const float* Wm2; const float* Wu2;
    const float* Wout;
    const float* x; const int* ei;
    ushort_t* wswz;    // 3 * 32768
    ushort_t* woswz;   // 4096
    ushort_t* xb;      // N*128
    int* tails;        // NB*TSTRIDE + cursor (zeroed together)
    int* flag;
    int N, E, TI;
    int ZT, WB, XB;
};
__global__ __launch_bounds__(256) void setup_kernel(SetupArgs a) {
    int bx = blockIdx.x, t = threadIdx.x;
    if (bx < a.ZT) {
        int i = bx * 256 + t;
        if (i < a.TI) a.tails[i] = 0;
        return;
    }
    bx -= a.ZT;
    if (bx == 0) {
        __shared__ int any;
        if (t == 0) any = 0;
        __syncthreads();
        int n = a.E < 2048 ? a.E : 2048;
        for (int i = t; i < n; i += 256)
            if (a.ei[2 * i + 1] != 0) any = 1;
        __syncthreads();
        if (t == 0) a.flag[0] = any;
        return;
    }
    bx -= 1;
    if (bx < a.WB) {
        int i = bx * 256 + t;
        if (i < 3 * 32768) {
            int l = i >> 15, r2 = i & 32767;
            int ct = r2 >> 12, ks = (r2 >> 9) & 7, lane = (r2 >> 3) & 63, j = r2 & 7;
            int col = ct * 16 + (lane & 15);
            int k = ks * 32 + (lane >> 4) * 8 + j;
            const float* Wm = l == 0 ? a.Wm0 : (l == 1 ? a.Wm1 : a.Wm2);
            const float* Wu = l == 0 ? a.Wu0 : (l == 1 ? a.Wu1 : a.Wu2);
            float v = k < 128 ? Wm[col * 128 + k] : Wu[col * 128 + (k - 128)];
            a.wswz[(size_t)l * 32768 + r2] = f2bf(v);
        } else if (i < 3 * 32768 + 4096) {
            int r2 = i - 3 * 32768;
            int ct = r2 >> 11, ks = (r2 >> 9) & 3, lane = (r2 >> 3) & 63, j = r2 & 7;
            int col = ct * 16 + (lane & 15);
            int k = ks * 32 + (lane >> 4) * 8 + j;
            a.woswz[r2] = f2bf(a.Wout[col * 128 + k]);
        }
        return;
    }
    bx -= a.WB;
    {
        int j = bx * 256 + t;
        if (j < a.N * 32) {
            float4 v = *(const float4*)(a.x + (size_t)j * 4);
            uint2 o;
            o.x = packbf(v.x, v.y);
            o.y = packbf(v.z, v.w);
            *(uint2*)(a.xb + (size_t)j * 4) = o;
        }
    }
}

// ---------------------------------------------------------------------------
// Phase A: LDS multi-split binning. R17: LDS counting-sort by bucket before
// the global scatter (place_kernel's proven pattern) -> coalesced runs.
// ---------------------------------------------------------------------------
__global__ __launch_bounds__(256) void bin_kernel(
    const int* __restrict__ ei, const float* __restrict__ ew,
    const int* __restrict__ flag, int* __restrict__ tails,
    uint2* __restrict__ staged, int E, int NB) {
    __shared__ uint2 ent[EPB];           // 16 KB
    __shared__ uint2 srt[EPB];           // 16 KB
    __shared__ int cnt[256], cur[256], exc[256], runbase[256];
    const int tid = threadIdx.x;
    const int e0 = blockIdx.x * EPB;
    const int nE = (E - e0) < EPB ? (E - e0) : EPB;
    const int f = flag[0];
    cnt[tid] = 0;
    cur[tid] = 0;
    __syncthreads();
    for (int i = tid; i < nE; i += 256) {
        int e = e0 + i;
        int s = get_src(ei, e, E, f);
        int d = get_dst(ei, e, E, f);
        uint2 v;
        v.x = (uint_t)s | ((uint_t)f2bf(ew[e]) << 16);
        v.y = (uint_t)d;
        ent[i] = v;
        atomicAdd(&cnt[d >> BSH], 1);    // LDS atomic
    }
    __syncthreads();
    // in-place inclusive scan of cnt into exc, then convert to exclusive
    exc[tid] = cnt[tid];
    __syncthreads();
    for (int o = 1; o < 256; o <<= 1) {
        int v = tid >= o ? exc[tid - o] : 0;
        __syncthreads();
        exc[tid] += v;
        __syncthreads();
    }
    exc[tid] -= cnt[tid];
    if (tid < NB) {
        int c = cnt[tid];
        runbase[tid] = c ? atomicAdd(&tails[tid * TSTRIDE], c) : 0;
    }
    __syncthreads();
    // counting-sort into srt (bucket-contiguous local image)
    for (int i = tid; i < nE; i += 256) {
        uint2 v = ent[i];
        int b = (int)(v.y >> BSH);
        int lp = atomicAdd(&cur[b], 1);  // LDS atomic
        srt[exc[b] + lp] = v;
    }
    __syncthreads();
    // coalesced write-out: consecutive i -> consecutive gp within runs
    for (int i = tid; i < nE; i += 256) {
        uint2 v = srt[i];
        int b = (int)(v.y >> BSH);
        int gp = runbase[b] + (i - exc[b]);
        if (gp < CAPB) {
            uint2 o;
            o.x = v.x;
            o.y = (uint_t)(v.y & (BSZ - 1));
            staged[(size_t)b * CAPB + gp] = o;
        }
    }
}

// ---------------------------------------------------------------------------
// Phase B: one block per bucket -> contiguous CSR region + rowdeg{beg,end}.
// ---------------------------------------------------------------------------
__global__ __launch_bounds__(256) void place_kernel(
    const uint2* __restrict__ staged, const int* __restrict__ tails,
    int* __restrict__ cursor, uint_t* __restrict__ csr,
    int2* __restrict__ rowdeg, int N) {
    __shared__ int cnt[256], cur[256], excl[256], sm[256];
    __shared__ int baseSh;
    __shared__ uint_t outb[CAPB];        // 24 KB
    const int b = blockIdx.x, tid = threadIdx.x;
    const int node0 = b << BSH;
    int tot = tails[b * TSTRIDE];
    tot = tot < CAPB ? tot : CAPB;
    cnt[tid] = 0;
    __syncthreads();
    const uint2* sp = staged + ((size_t)b * CAPB);
    for (int i = tid; i < tot; i += 256) atomicAdd(&cnt[sp[i].y], 1);
    __syncthreads();
    int c0 = cnt[tid];
    sm[tid] = c0;
    __syncthreads();
    for (int o = 1; o < 256; o <<= 1) {
        int v = tid >= o ? sm[tid - o] : 0;
        __syncthreads();
        sm[tid] += v;
        __syncthreads();
    }
    if (tid == 255) baseSh = atomicAdd(cursor, sm[255]);
    excl[tid] = sm[tid] - c0;
    cur[tid] = 0;
    __syncthreads();
    const int base = baseSh;
    for (int i = tid; i < tot; i += 256) {
        uint2 e = sp[i];
        int pos = excl[e.y] + atomicAdd(&cur[e.y], 1);
        outb[pos] = e.x;
    }
    __syncthreads();
    for (int i = tid; i < tot; i += 256) csr[base + i] = outb[i];
    if (node0 + tid < N) {
        int2 be;
        be.x = base + excl[tid];
        be.y = base + excl[tid] + c0;
        rowdeg[node0 + tid] = be;
    }
}

// ---------------------------------------------------------------------------
// Fused layer: block(256)=4 waves owns 16 rows.
//   phase1: wave wv aggregates nodes R0+wv*4..+3 into swizzled LDS Gt.
//           Deep gather: 4 edges/slot per batch (12 independent loads),
//           clamp-to-last + w=0 padding. H-tile issue-early/write-late.
//   phase2: wave wv computes all 16 rows x cols [32*wv,32*wv+32):
//           h' = tanh([Gt|Ht] @ Wswz + bu), W-frags in registers.
//   WITH_OUT: h3 -> Gt (swizzled), waves 0-1 do out = h3 @ Woswz + bout.
// LDS swizzle (ushort units): 8-elem block bb of row r at bb ^ (r&7)
// -> ds_read_b128 A-frags are 2-way conflicts (free, m136).
// ---------------------------------------------------------------------------
#define ACC16(W, V0, V1)                                         \
    do {                                                         \
        s[0] += (W) * bf_lo((V0).x);  s[1] += (W) * bf_hi((V0).x);  \
        s[2] += (W) * bf_lo((V0).y);  s[3] += (W) * bf_hi((V0).y);  \
        s[4] += (W) * bf_lo((V0).z);  s[5] += (W) * bf_hi((V0).z);  \
        s[6] += (W) * bf_lo((V0).w);  s[7] += (W) * bf_hi((V0).w);  \
        s[8] += (W) * bf_lo((V1).x);  s[9] += (W) * bf_hi((V1).x);  \
        s[10] += (W) * bf_lo((V1).y); s[11] += (W) * bf_hi((V1).y); \
        s[12] += (W) * bf_lo((V1).z); s[13] += (W) * bf_hi((V1).z); \
        s[14] += (W) * bf_lo((V1).w); s[15] += (W) * bf_hi((V1).w); \
    } while (0)

template <int WITH_OUT>
__global__ __launch_bounds__(256, 4) void fused_layer(
    const uint_t* __restrict__ csr, const int2* __restrict__ rowdeg,
    const ushort_t* __restrict__ h, const ushort_t* __restrict__ Wswz,
    const float* __restrict__ bias, ushort_t* __restrict__ Hout,
    const ushort_t* __restrict__ Woswz, const float* __restrict__ bout,
    float* __restrict__ Cout, int N) {
    __shared__ ushort_t Gt[16 * 128];    // 4 KB, swizzled
    __shared__ ushort_t Ht[16 * 128];    // 4 KB, swizzled
    const int tid = threadIdx.x;
    const int lane = tid & 63;
    const int wv = tid >> 6;
    const int R0 = blockIdx.x * 16;
    const int slot = lane >> 3, f8 = lane & 7;

    // -- T14 issue-early: H-tile load with pre-swizzled source ------------
    const int pp = tid * 16;                  // LDS byte pos (256*16B = 4KB)
    const int srow = pp >> 8;                 // local row 0..15
    const int sx = (pp & 255) ^ ((srow & 7) << 4);
    uint4 hst = *(const uint4*)(h + (size_t)(R0 + srow) * 128 + (sx >> 1));

    // -- phase 1: aggregation of 4 nodes per wave, 4-deep edge batches ----
#pragma unroll
    for (int i = 0; i < 4; ++i) {
        const int lr = wv * 4 + i;
        const int nd = R0 + lr;
        int beg = 0, end = 0;
        if (nd < N) { int2 be = rowdeg[nd]; beg = be.x; end = be.y; }
        float s[16];
#pragma unroll
        for (int k = 0; k < 16; ++k) s[k] = 0.f;
        for (int j = beg + slot; j < end; j += 32) {
            const int last = end - 1;
            const int j1 = (j + 8) < last ? (j + 8) : last;
            const int j2 = (j + 16) < last ? (j + 16) : last;
            const int j3 = (j + 24) < last ? (j + 24) : last;
            uint_t p0 = csr[j];
            uint_t p1 = csr[j1];
            uint_t p2 = csr[j2];
            uint_t p3 = csr[j3];
            const ushort_t* r0 = h + (size_t)(p0 & 0xFFFFu) * 128 + f8 * 16;
            const ushort_t* r1 = h + (size_t)(p1 & 0xFFFFu) * 128 + f8 * 16;
            const ushort_t* r2 = h + (size_t)(p2 & 0xFFFFu) * 128 + f8 * 16;
            const ushort_t* r3 = h + (size_t)(p3 & 0xFFFFu) * 128 + f8 * 16;
            uint4 a0 = *(const uint4*)(r0);
            uint4 a1 = *(const uint4*)(r0 + 8);
            uint4 b0 = *(const uint4*)(r1);
            uint4 b1 = *(const uint4*)(r1 + 8);
            uint4 c0 = *(const uint4*)(r2);
            uint4 c1 = *(const uint4*)(r2 + 8);
            uint4 d0 = *(const uint4*)(r3);
            uint4 d1 = *(const uint4*)(r3 + 8);
            float w0 = bf_hi(p0);
            float w1 = (j + 8) < end ? bf_hi(p1) : 0.f;
            float w2 = (j + 16) < end ? bf_hi(p2) : 0.f;
            float w3 = (j + 24) < end ? bf_hi(p3) : 0.f;
            ACC16(w0, a0, a1);
            ACC16(w1, b0, b1);
            ACC16(w2, c0, c1);
            ACC16(w3, d0, d1);
        }
#pragma unroll
        for (int k = 0; k < 16; ++k) s[k] += __shfl_xor(s[k], 8, 64);
#pragma unroll
        for (int k = 0; k < 16; ++k) s[k] += __shfl_xor(s[k], 16, 64);
#pragma unroll
        for (int k = 0; k < 16; ++k) s[k] += __shfl_xor(s[k], 32, 64);
        if (slot == 0) {
            uint4 o0, o1;
            o0.x = packbf(s[0], s[1]);   o0.y = packbf(s[2], s[3]);
            o0.z = packbf(s[4], s[5]);   o0.w = packbf(s[6], s[7]);
            o1.x = packbf(s[8], s[9]);   o1.y = packbf(s[10], s[11]);
            o1.z = packbf(s[12], s[13]); o1.w = packbf(s[14], s[15]);
            const int sw = (lr & 7) << 3;
            *(uint4*)(Gt + lr * 128 + ((f8 * 16) ^ sw)) = o0;
            *(uint4*)(Gt + lr * 128 + ((f8 * 16 + 8) ^ sw)) = o1;
        }
    }
    // -- write-late H tile ------------------------------------------------
    *(uint4*)((char*)Ht + pp) = hst;
    __syncthreads();

    // -- phase 2: MFMA. wave wv: all 16 rows, cols [32*wv, 32*wv+32) ------
    const int m = lane & 15, kg = lane >> 4;
    const int lsw = (m & 7) << 3;
    const int colL = lane & 15, rq = lane >> 4;

    short8 b0f[8], b1f[8];
#pragma unroll
    for (int ksp = 0; ksp < 8; ++ksp) {
        b0f[ksp] = *(const short8*)(Wswz + (((2 * wv) * 8 + ksp) * 64 + lane) * 8);
        b1f[ksp] = *(const short8*)(Wswz + (((2 * wv + 1) * 8 + ksp) * 64 + lane) * 8);
    }
    const float bv0 = bias[(2 * wv) * 16 + colL];
    const float bv1 = bias[(2 * wv + 1) * 16 + colL];

    f32x4 acc0 = (f32x4){0.f, 0.f, 0.f, 0.f};
    f32x4 acc1 = (f32x4){0.f, 0.f, 0.f, 0.f};
#pragma unroll
    for (int ksp = 0; ksp < 8; ++ksp) {
        const ushort_t* tp = (ksp < 4) ? Gt : Ht;
        short8 av = *(const short8*)(tp + m * 128 + (((ksp & 3) * 32 + kg * 8) ^ lsw));
        acc0 = __builtin_amdgcn_mfma_f32_16x16x32_bf16(av, b0f[ksp], acc0, 0, 0, 0);
        acc1 = __builtin_amdgcn_mfma_f32_16x16x32_bf16(av, b1f[ksp], acc1, 0, 0, 0);
    }
    float v0[4], v1[4];
#pragma unroll
    for (int reg = 0; reg < 4; ++reg) {
        v0[reg] = fast_tanh(acc0[reg] + bv0);
        v1[reg] = fast_tanh(acc1[reg] + bv1);
    }

    if (WITH_OUT == 0) {
#pragma unroll
        for (int reg = 0; reg < 4; ++reg) {
            int gr = R0 + rq * 4 + reg;
            if (gr < N) {
                Hout[(size_t)gr * 128 + (2 * wv) * 16 + colL] = f2bf(v0[reg]);
                Hout[(size_t)gr * 128 + (2 * wv + 1) * 16 + colL] = f2bf(v1[reg]);
            }
        }
    } else {
        // h3 -> Gt (swizzled), then out = h3 @ Woswz + bout
        __syncthreads();   // all A-reads of Gt done before overwrite
#pragma unroll
        for (int reg = 0; reg < 4; ++reg) {
            int lr3 = rq * 4 + reg;
            int sw3 = (lr3 & 7) << 3;
            Gt[lr3 * 128 + (((2 * wv) * 16 + colL) ^ sw3)] = f2bf(v0[reg]);
            Gt[lr3 * 128 + (((2 * wv + 1) * 16 + colL) ^ sw3)] = f2bf(v1[reg]);
        }
        __syncthreads();
        if (wv < 2) {
            const int oc = wv;               // col tile 0..1
            const int osw = (m & 7) << 3;
            short8 ob[4];
#pragma unroll
            for (int ks = 0; ks < 4; ++ks)
                ob[ks] = *(const short8*)(Woswz + ((oc * 4 + ks) * 64 + lane) * 8);
            f32x4 oacc = (f32x4){0.f, 0.f, 0.f, 0.f};
#pragma unroll
            for (int ks = 0; ks < 4; ++ks) {
                short8 av = *(const short8*)(Gt + m * 128 + ((ks * 32 + kg * 8) ^ osw));
                oacc = __builtin_amdgcn_mfma_f32_16x16x32_bf16(av, ob[ks], oacc, 0, 0, 0);
            }
            const float obv = bout[oc * 16 + colL];
#pragma unroll
            for (int reg = 0; reg < 4; ++reg) {
                int gr = R0 + rq * 4 + reg;
                if (gr < N) Cout[(size_t)gr * 32 + oc * 16 + colL] = oacc[reg] + obv;
            }
        }
    }
}

extern "C" void kernel_launch(void* const* d_in, const int* in_sizes, int n_in,
                              void* d_out, int out_size, void* d_ws, size_t ws_size,
                              hipStream_t stream) {
    const float* x   = (const float*)d_in[0];
    const int* ei    = (const int*)d_in[1];
    const float* ew  = (const float*)d_in[2];
    const float* Wm[3] = {(const float*)d_in[3], (const float*)d_in[6], (const float*)d_in[9]};
    const float* Wu[3] = {(const float*)d_in[4], (const float*)d_in[7], (const float*)d_in[10]};
    const float* bu[3] = {(const float*)d_in[5], (const float*)d_in[8], (const float*)d_in[11]};
    const float* Wout = (const float*)d_in[12];
    const float* bout = (const float*)d_in[13];
    float* out = (float*)d_out;

    const int N = in_sizes[0] / 128;
    const int E = in_sizes[2];
    const size_t NPAD = 50048;
    const int NB = (N + BSZ - 1) / BSZ;  // 196 buckets
    const int TI = NB * TSTRIDE + 16;    // tails + cursor (zeroed together)

    ushort_t* xb    = (ushort_t*)d_ws;              // [NPAD,128] bf16
    ushort_t* hA    = xb + NPAD * 128;
    ushort_t* hB    = hA + NPAD * 128;
    ushort_t* gbuf  = hB + NPAD * 128;              // unused (kept for layout)
    ushort_t* wswz  = gbuf + NPAD * 128;            // 3*32768 bf16
    ushort_t* woswz = wswz + 3 * 32768;             // 4096 bf16
    int* flag       = (int*)(woswz + 4096);
    int* tails      = flag + 1;
    int* cursor     = tails + NB * TSTRIDE;         // inside zeroed TI range
    int* endp       = tails + TI;
    int2* rowdeg    = (int2*)(((uintptr_t)endp + 7) & ~(uintptr_t)7);
    uint2* staged   = (uint2*)(rowdeg + N + 8);
    uint_t* csr     = (uint_t*)(staged + (size_t)NB * CAPB);
    (void)ws_size;

    const int ZT = (TI + 255) / 256;
    const int WB = (3 * 32768 + 4096 + 255) / 256;  // 400
    const int XB = (N * 32 + 255) / 256;            // 6250
    const int gB = (E + EPB - 1) / EPB;             // 391
    const int gF = (N + 15) / 16;                   // 3125

    SetupArgs sa;
    sa.Wm0 = Wm[0]; sa.Wu0 = Wu[0];
    sa.Wm1 = Wm[1]; sa.Wu1 = Wu[1];
    sa.Wm2 = Wm[2]; sa.Wu2 = Wu[2];
    sa.Wout = Wout; sa.x = x; sa.ei = ei;
    sa.wswz = wswz; sa.woswz = woswz; sa.xb = xb;
    sa.tails = tails; sa.flag = flag;
    sa.N = N; sa.E = E; sa.TI = TI;
    sa.ZT = ZT; sa.WB = WB; sa.XB = XB;
    setup_kernel<<<ZT + 1 + WB + XB, 256, 0, stream>>>(sa);

    bin_kernel<<<gB, 256, 0, stream>>>(ei, ew, flag, tails, staged, E, NB);
    place_kernel<<<NB, 256, 0, stream>>>(staged, tails, cursor, csr, rowdeg, N);

    fused_layer<0><<<gF, 256, 0, stream>>>(csr, rowdeg, xb, wswz, bu[0], hA,
                                           nullptr, nullptr, nullptr, N);
    fused_layer<0><<<gF, 256, 0, stream>>>(csr, rowdeg, hA, wswz + 32768, bu[1], hB,
                                           nullptr, nullptr, nullptr, N);
    fused_layer<1><<<gF, 256, 0, stream>>>(csr, rowdeg, hB, wswz + 2 * 32768, bu[2],
                                           nullptr, woswz, bout, out, N);
}

// Round 9
// 247.967 us; speedup vs baseline: 1.1776x; 1.0422x over previous
//
#include <hip/hip_runtime.h>
#include <hip/hip_bf16.h>
#include <cstddef>

// ---------------------------------------------------------------------------
// 3-layer MPNN, N=50000, E=800000, D=128, OUT=32.
// R21 = R20 minus the oversized VALU sched_group_barrier groups (prime
// suspect for the compile-time hang -> "container failed twice": SGB(VALU,
// 300) forces the scheduler to satisfy a grouping constraint over a huge DAG
// region). Keep only the VMEM-read clustering (count 8/4) -- that's the part
// that forces all gather loads to issue before the first consume (Little's
// law); consume order after them is implied by data deps.
// Base: R17 datapath (verified @258us). csr entries preloaded in lanes 0-31
// + shfl broadcast; 8/4 independent row loads; clamp-to-last + w=0 padding;
// deg>32 rare scalar tail. Phase 2 (MFMA, W-in-regs, XOR-swizzled Gt/Ht),
// bin/place/setup = R17.  CSR entry: (src:u16 | w:bf16<<16).
// ---------------------------------------------------------------------------

typedef __attribute__((ext_vector_type(8))) short short8;
typedef __attribute__((ext_vector_type(4))) float f32x4;
typedef unsigned short ushort_t;
typedef unsigned int uint_t;
typedef __attribute__((ext_vector_type(4))) uint_t u32x4;

#define BSH 8               // bucket shift: 256 nodes per bucket
#define BSZ 256             // nodes per bucket
#define CAPB 6144           // staged entries per bucket (mean 4096, >30 sigma)
#define TSTRIDE 16          // tails counter stride in ints (64B line each)
#define EPB 2048            // edges per bin block

__device__ inline ushort_t f2bf(float f) {  // round-to-nearest-even
    uint_t u = __float_as_uint(f);
    uint_t r = u + 0x7FFFu + ((u >> 16) & 1u);
    return (ushort_t)(r >> 16);
}
__device__ inline float bf_lo(uint_t u) { return __uint_as_float(u << 16); }
__device__ inline float bf_hi(uint_t u) { return __uint_as_float(u & 0xFFFF0000u); }
__device__ inline uint_t packbf(float a, float b) {
    return (uint_t)f2bf(a) | ((uint_t)f2bf(b) << 16);
}

// fast tanh: 1 - 2/(exp2(2*log2e*x)+1); saturates correctly at +-inf.
__device__ inline float fast_tanh(float x) {
    float e = __builtin_amdgcn_exp2f(x * 2.8853900817779268f);
    return 1.f - 2.f * __builtin_amdgcn_rcpf(e + 1.f);
}

// flag=1 -> int32 [2][E]; flag=0 -> int64 [2][E] (vectorized low-word read)
__device__ inline int get_dst(const int* __restrict__ ei, int e, int E, int f) {
    if (f) return ei[E + e];
    return ((const int2*)ei)[(size_t)E + e].x;
}
__device__ inline int get_src(const int* __restrict__ ei, int e, int E, int f) {
    if (f) return ei[e];
    return ((const int2*)ei)[e].x;
}

// ---------------------------------------------------------------------------
// Fused setup: zero tails+cursor | detect idx layout | swizzled bf16 weights
// | x -> bf16.
// ---------------------------------------------------------------------------
struct SetupArgs {
    const float* Wm0; const float* Wu0;
    const float* Wm1; const float* Wu1;
    const float* Wm2; const float* Wu2;
    const float* Wout;
    const float* x; const int* ei;
    ushort_t* wswz;    // 3 * 32768
    ushort_t* woswz;   // 4096
    ushort_t* xb;      // N*128
    int* tails;        // NB*TSTRIDE + cursor (zeroed together)
    int* flag;
    int N, E, TI;
    int ZT, WB, XB;
};
__global__ __launch_bounds__(256) void setup_kernel(SetupArgs a) {
    int bx = blockIdx.x, t = threadIdx.x;
    if (bx < a.ZT) {
        int i = bx * 256 + t;
        if (i < a.TI) a.tails[i] = 0;
        return;
    }
    bx -= a.ZT;
    if (bx == 0) {
        __shared__ int any;
        if (t == 0) any = 0;
        __syncthreads();
        int n = a.E < 2048 ? a.E : 2048;
        for (int i = t; i < n; i += 256)
            if (a.ei[2 * i + 1] != 0) any = 1;
        __syncthreads();
        if (t == 0) a.flag[0] = any;
        return;
    }
    bx -= 1;
    if (bx < a.WB) {
        int i = bx * 256 + t;
        if (i < 3 * 32768) {
            int l = i >> 15, r2 = i & 32767;
            int ct = r2 >> 12, ks = (r2 >> 9) & 7, lane = (r2 >> 3) & 63, j = r2 & 7;
            int col = ct * 16 + (lane & 15);
            int k = ks * 32 + (lane >> 4) * 8 + j;
            const float* Wm = l == 0 ? a.Wm0 : (l == 1 ? a.Wm1 : a.Wm2);
            const float* Wu = l == 0 ? a.Wu0 : (l == 1 ? a.Wu1 : a.Wu2);
            float v = k < 128 ? Wm[col * 128 + k] : Wu[col * 128 + (k - 128)];
            a.wswz[(size_t)l * 32768 + r2] = f2bf(v);
        } else if (i < 3 * 32768 + 4096) {
            int r2 = i - 3 * 32768;
            int ct = r2 >> 11, ks = (r2 >> 9) & 3, lane = (r2 >> 3) & 63, j = r2 & 7;
            int col = ct * 16 + (lane & 15);
            int k = ks * 32 + (lane >> 4) * 8 + j;
            a.woswz[r2] = f2bf(a.Wout[col * 128 + k]);
        }
        return;
    }
    bx -= a.WB;
    {
        int j = bx * 256 + t;
        if (j < a.N * 32) {
            float4 v = *(const float4*)(a.x + (size_t)j * 4);
            uint2 o;
            o.x = packbf(v.x, v.y);
            o.y = packbf(v.z, v.w);
            *(uint2*)(a.xb + (size_t)j * 4) = o;
        }
    }
}

// ---------------------------------------------------------------------------
// Phase A: LDS multi-split binning + counting-sort -> coalesced scatter.
// ---------------------------------------------------------------------------
__global__ __launch_bounds__(256) void bin_kernel(
    const int* __restrict__ ei, const float* __restrict__ ew,
    const int* __restrict__ flag, int* __restrict__ tails,
    uint2* __restrict__ staged, int E, int NB) {
    __shared__ uint2 ent[EPB];           // 16 KB
    __shared__ uint2 srt[EPB];           // 16 KB
    __shared__ int cnt[256], cur[256], exc[256], runbase[256];
    const int tid = threadIdx.x;
    const int e0 = blockIdx.x * EPB;
    const int nE = (E - e0) < EPB ? (E - e0) : EPB;
    const int f = flag[0];
    cnt[tid] = 0;
    cur[tid] = 0;
    __syncthreads();
    for (int i = tid; i < nE; i += 256) {
        int e = e0 + i;
        int s = get_src(ei, e, E, f);
        int d = get_dst(ei, e, E, f);
        uint2 v;
        v.x = (uint_t)s | ((uint_t)f2bf(ew[e]) << 16);
        v.y = (uint_t)d;
        ent[i] = v;
        atomicAdd(&cnt[d >> BSH], 1);    // LDS atomic
    }
    __syncthreads();
    exc[tid] = cnt[tid];
    __syncthreads();
    for (int o = 1; o < 256; o <<= 1) {
        int v = tid >= o ? exc[tid - o] : 0;
        __syncthreads();
        exc[tid] += v;
        __syncthreads();
    }
    exc[tid] -= cnt[tid];
    if (tid < NB) {
        int c = cnt[tid];
        runbase[tid] = c ? atomicAdd(&tails[tid * TSTRIDE], c) : 0;
    }
    __syncthreads();
    for (int i = tid; i < nE; i += 256) {
        uint2 v = ent[i];
        int b = (int)(v.y >> BSH);
        int lp = atomicAdd(&cur[b], 1);  // LDS atomic
        srt[exc[b] + lp] = v;
    }
    __syncthreads();
    for (int i = tid; i < nE; i += 256) {
        uint2 v = srt[i];
        int b = (int)(v.y >> BSH);
        int gp = runbase[b] + (i - exc[b]);
        if (gp < CAPB) {
            uint2 o;
            o.x = v.x;
            o.y = (uint_t)(v.y & (BSZ - 1));
            staged[(size_t)b * CAPB + gp] = o;
        }
    }
}

// ---------------------------------------------------------------------------
// Phase B: one block per bucket -> contiguous CSR region + rowdeg{beg,end}.
// ---------------------------------------------------------------------------
__global__ __launch_bounds__(256) void place_kernel(
    const uint2* __restrict__ staged, const int* __restrict__ tails,
    int* __restrict__ cursor, uint_t* __restrict__ csr,
    int2* __restrict__ rowdeg, int N) {
    __shared__ int cnt[256], cur[256], excl[256], sm[256];
    __shared__ int baseSh;
    __shared__ uint_t outb[CAPB];        // 24 KB
    const int b = blockIdx.x, tid = threadIdx.x;
    const int node0 = b << BSH;
    int tot = tails[b * TSTRIDE];
    tot = tot < CAPB ? tot : CAPB;
    cnt[tid] = 0;
    __syncthreads();
    const uint2* sp = staged + ((size_t)b * CAPB);
    for (int i = tid; i < tot; i += 256) atomicAdd(&cnt[sp[i].y], 1);
    __syncthreads();
    int c0 = cnt[tid];
    sm[tid] = c0;
    __syncthreads();
    for (int o = 1; o < 256; o <<= 1) {
        int v = tid >= o ? sm[tid - o] : 0;
        __syncthreads();
        sm[tid] += v;
        __syncthreads();
    }
    if (tid == 255) baseSh = atomicAdd(cursor, sm[255]);
    excl[tid] = sm[tid] - c0;
    cur[tid] = 0;
    __syncthreads();
    const int base = baseSh;
    for (int i = tid; i < tot; i += 256) {
        uint2 e = sp[i];
        int pos = excl[e.y] + atomicAdd(&cur[e.y], 1);
        outb[pos] = e.x;
    }
    __syncthreads();
    for (int i = tid; i < tot; i += 256) csr[base + i] = outb[i];
    if (node0 + tid < N) {
        int2 be;
        be.x = base + excl[tid];
        be.y = base + excl[tid] + c0;
        rowdeg[node0 + tid] = be;
    }
}

// ---------------------------------------------------------------------------
// Fused layer: block(256)=4 waves owns 16 rows.
// Phase 1: per wave 4 nodes; csr entries preloaded in lanes 0-31 and
// shfl-broadcast; 8 (deg>16) or 4 independent row loads clustered via
// sched_group_barrier(VMEM_READ only); clamp + w=0 padding; deg>32 tail.
// Phase 2: wave wv computes all 16 rows x cols [32*wv,32*wv+32), W in regs,
// A from XOR-swizzled LDS Gt/Ht. WITH_OUT: fold output GEMM via LDS h3.
// ---------------------------------------------------------------------------
template <int WITH_OUT>
__global__ __launch_bounds__(256, 4) void fused_layer(
    const uint_t* __restrict__ csr, const int2* __restrict__ rowdeg,
    const ushort_t* __restrict__ h, const ushort_t* __restrict__ Wswz,
    const float* __restrict__ bias, ushort_t* __restrict__ Hout,
    const ushort_t* __restrict__ Woswz, const float* __restrict__ bout,
    float* __restrict__ Cout, int N) {
    __shared__ ushort_t Gt[16 * 128];    // 4 KB, swizzled
    __shared__ ushort_t Ht[16 * 128];    // 4 KB, swizzled
    const int tid = threadIdx.x;
    const int lane = tid & 63;
    const int wv = tid >> 6;
    const int R0 = blockIdx.x * 16;
    const int sl = lane >> 4, fl = lane & 15;

    // -- T14 issue-early: H-tile load with pre-swizzled source ------------
    const int pp = tid * 16;                  // LDS byte pos (256*16B = 4KB)
    const int srow = pp >> 8;                 // local row 0..15
    const int sx = (pp & 255) ^ ((srow & 7) << 4);
    uint4 hst = *(const uint4*)(h + (size_t)(R0 + srow) * 128 + (sx >> 1));

    // -- per-node metadata + first-32 csr entries (lanes 0-31, clamped) ---
    int begs[4], degs[4];
    uint_t cent[4];
#pragma unroll
    for (int i = 0; i < 4; ++i) {
        int nd = R0 + wv * 4 + i;
        int bg = 0, dg = 0;
        if (nd < N) { int2 be = rowdeg[nd]; bg = be.x; dg = be.y - be.x; }
        begs[i] = bg; degs[i] = dg;
        cent[i] = 0;
        if (dg > 0) {
            int idx = lane & 31;
            idx = idx < dg ? idx : dg - 1;
            cent[i] = csr[bg + idx];
        }
    }

    float sacc[4][8];
#pragma unroll
    for (int i = 0; i < 4; ++i)
#pragma unroll
        for (int r = 0; r < 8; ++r) sacc[i][r] = 0.f;

    // -- phase 1: gather, 4 nodes; loads clustered via sched_group_barrier
#pragma unroll
    for (int i = 0; i < 4; ++i) {
        uint_t pw[8];
        const ushort_t* ra[8];
#pragma unroll
        for (int b = 0; b < 8; ++b) {
            uint_t p = __shfl(cent[i], (b * 4 + sl) & 31, 64);
            pw[b] = p;
            ra[b] = h + (size_t)(p & 0xFFFFu) * 128 + fl * 8;
        }
        u32x4 v[8];
        if (degs[i] > 16) {              // wave-uniform branch
#pragma unroll
            for (int b = 0; b < 8; ++b) v[b] = *(const u32x4*)ra[b];
            __builtin_amdgcn_sched_group_barrier(0x020, 8, 0);   // 8 VMEM reads first
#pragma unroll
            for (int b = 0; b < 8; ++b) {
                float w = ((b * 4 + sl) < degs[i]) ? bf_hi(pw[b]) : 0.f;
                sacc[i][0] += w * bf_lo(v[b][0]); sacc[i][1] += w * bf_hi(v[b][0]);
                sacc[i][2] += w * bf_lo(v[b][1]); sacc[i][3] += w * bf_hi(v[b][1]);
                sacc[i][4] += w * bf_lo(v[b][2]); sacc[i][5] += w * bf_hi(v[b][2]);
                sacc[i][6] += w * bf_lo(v[b][3]); sacc[i][7] += w * bf_hi(v[b][3]);
            }
        } else {
#pragma unroll
            for (int b = 0; b < 4; ++b) v[b] = *(const u32x4*)ra[b];
            __builtin_amdgcn_sched_group_barrier(0x020, 4, 0);   // 4 VMEM reads first
#pragma unroll
            for (int b = 0; b < 4; ++b) {
                float w = ((b * 4 + sl) < degs[i]) ? bf_hi(pw[b]) : 0.f;
                sacc[i][0] += w * bf_lo(v[b][0]); sacc[i][1] += w * bf_hi(v[b][0]);
                sacc[i][2] += w * bf_lo(v[b][1]); sacc[i][3] += w * bf_hi(v[b][1]);
                sacc[i][4] += w * bf_lo(v[b][2]); sacc[i][5] += w * bf_hi(v[b][2]);
                sacc[i][6] += w * bf_lo(v[b][3]); sacc[i][7] += w * bf_hi(v[b][3]);
            }
        }
        if (degs[i] > 32) {              // rare tail (~1e-4 of nodes)
            for (int j = begs[i] + 32 + sl; j < begs[i] + degs[i]; j += 4) {
                uint_t p = csr[j];
                float w = bf_hi(p);
                u32x4 vv = *(const u32x4*)(h + (size_t)(p & 0xFFFFu) * 128 + fl * 8);
                sacc[i][0] += w * bf_lo(vv[0]); sacc[i][1] += w * bf_hi(vv[0]);
                sacc[i][2] += w * bf_lo(vv[1]); sacc[i][3] += w * bf_hi(vv[1]);
                sacc[i][4] += w * bf_lo(vv[2]); sacc[i][5] += w * bf_hi(vv[2]);
                sacc[i][6] += w * bf_lo(vv[3]); sacc[i][7] += w * bf_hi(vv[3]);
            }
        }
    }

    // -- reduce over 4 slots, pack, write swizzled Gt rows ----------------
#pragma unroll
    for (int i = 0; i < 4; ++i) {
#pragma unroll
        for (int r = 0; r < 8; ++r) {
            sacc[i][r] += __shfl_xor(sacc[i][r], 16, 64);
            sacc[i][r] += __shfl_xor(sacc[i][r], 32, 64);
        }
        if (sl == 0) {
            uint4 o;
            o.x = packbf(sacc[i][0], sacc[i][1]);
            o.y = packbf(sacc[i][2], sacc[i][3]);
            o.z = packbf(sacc[i][4], sacc[i][5]);
            o.w = packbf(sacc[i][6], sacc[i][7]);
            const int lr = wv * 4 + i;
            *(uint4*)(Gt + lr * 128 + ((fl * 8) ^ ((lr & 7) << 3))) = o;
        }
    }
    // -- write-late H tile ------------------------------------------------
    *(uint4*)((char*)Ht + pp) = hst;
    __syncthreads();

    // -- phase 2: MFMA. wave wv: all 16 rows, cols [32*wv, 32*wv+32) ------
    const int m = lane & 15, kg = lane >> 4;
    const int lsw = (m & 7) << 3;
    const int colL = lane & 15, rq = lane >> 4;

    short8 b0f[8], b1f[8];
#pragma unroll
    for (int ksp = 0; ksp < 8; ++ksp) {
        b0f[ksp] = *(const short8*)(Wswz + (((2 * wv) * 8 + ksp) * 64 + lane) * 8);
        b1f[ksp] = *(const short8*)(Wswz + (((2 * wv + 1) * 8 + ksp) * 64 + lane) * 8);
    }
    const float bv0 = bias[(2 * wv) * 16 + colL];
    const float bv1 = bias[(2 * wv + 1) * 16 + colL];

    f32x4 acc0 = (f32x4){0.f, 0.f, 0.f, 0.f};
    f32x4 acc1 = (f32x4){0.f, 0.f, 0.f, 0.f};
#pragma unroll
    for (int ksp = 0; ksp < 8; ++ksp) {
        const ushort_t* tp = (ksp < 4) ? Gt : Ht;
        short8 av = *(const short8*)(tp + m * 128 + (((ksp & 3) * 32 + kg * 8) ^ lsw));
        acc0 = __builtin_amdgcn_mfma_f32_16x16x32_bf16(av, b0f[ksp], acc0, 0, 0, 0);
        acc1 = __builtin_amdgcn_mfma_f32_16x16x32_bf16(av, b1f[ksp], acc1, 0, 0, 0);
    }
    float v0[4], v1[4];
#pragma unroll
    for (int reg = 0; reg < 4; ++reg) {
        v0[reg] = fast_tanh(acc0[reg] + bv0);
        v1[reg] = fast_tanh(acc1[reg] + bv1);
    }

    if (WITH_OUT == 0) {
#pragma unroll
        for (int reg = 0; reg < 4; ++reg) {
            int gr = R0 + rq * 4 + reg;
            if (gr < N) {
                Hout[(size_t)gr * 128 + (2 * wv) * 16 + colL] = f2bf(v0[reg]);
                Hout[(size_t)gr * 128 + (2 * wv + 1) * 16 + colL] = f2bf(v1[reg]);
            }
        }
    } else {
        // h3 -> Gt (swizzled), then out = h3 @ Woswz + bout
        __syncthreads();   // all A-reads of Gt done before overwrite
#pragma unroll
        for (int reg = 0; reg < 4; ++reg) {
            int lr3 = rq * 4 + reg;
            int sw3 = (lr3 & 7) << 3;
            Gt[lr3 * 128 + (((2 * wv) * 16 + colL) ^ sw3)] = f2bf(v0[reg]);
            Gt[lr3 * 128 + (((2 * wv + 1) * 16 + colL) ^ sw3)] = f2bf(v1[reg]);
        }
        __syncthreads();
        if (wv < 2) {
            const int oc = wv;               // col tile 0..1
            const int osw = (m & 7) << 3;
            short8 ob[4];
#pragma unroll
            for (int ks = 0; ks < 4; ++ks)
                ob[ks] = *(const short8*)(Woswz + ((oc * 4 + ks) * 64 + lane) * 8);
            f32x4 oacc = (f32x4){0.f, 0.f, 0.f, 0.f};
#pragma unroll
            for (int ks = 0; ks < 4; ++ks) {
                short8 av = *(const short8*)(Gt + m * 128 + ((ks * 32 + kg * 8) ^ osw));
                oacc = __builtin_amdgcn_mfma_f32_16x16x32_bf16(av, ob[ks], oacc, 0, 0, 0);
            }
            const float obv = bout[oc * 16 + colL];
#pragma unroll
            for (int reg = 0; reg < 4; ++reg) {
                int gr = R0 + rq * 4 + reg;
                if (gr < N) Cout[(size_t)gr * 32 + oc * 16 + colL] = oacc[reg] + obv;
            }
        }
    }
}

extern "C" void kernel_launch(void* const* d_in, const int* in_sizes, int n_in,
                              void* d_out, int out_size, void* d_ws, size_t ws_size,
                              hipStream_t stream) {
    const float* x   = (const float*)d_in[0];
    const int* ei    = (const int*)d_in[1];
    const float* ew  = (const float*)d_in[2];
    const float* Wm[3] = {(const float*)d_in[3], (const float*)d_in[6], (const float*)d_in[9]};
    const float* Wu[3] = {(const float*)d_in[4], (const float*)d_in[7], (const float*)d_in[10]};
    const float* bu[3] = {(const float*)d_in[5], (const float*)d_in[8], (const float*)d_in[11]};
    const float* Wout = (const float*)d_in[12];
    const float* bout = (const float*)d_in[13];
    float* out = (float*)d_out;

    const int N = in_sizes[0] / 128;
    const int E = in_sizes[2];
    const size_t NPAD = 50048;
    const int NB = (N + BSZ - 1) / BSZ;  // 196 buckets
    const int TI = NB * TSTRIDE + 16;    // tails + cursor (zeroed together)

    ushort_t* xb    = (ushort_t*)d_ws;              // [NPAD,128] bf16
    ushort_t* hA    = xb + NPAD * 128;
    ushort_t* hB    = hA + NPAD * 128;
    ushort_t* gbuf  = hB + NPAD * 128;              // unused (kept for layout)
    ushort_t* wswz  = gbuf + NPAD * 128;            // 3*32768 bf16
    ushort_t* woswz = wswz + 3 * 32768;             // 4096 bf16
    int* flag       = (int*)(woswz + 4096);
    int* tails      = flag + 1;
    int* cursor     = tails + NB * TSTRIDE;         // inside zeroed TI range
    int* endp       = tails + TI;
    int2* rowdeg    = (int2*)(((uintptr_t)endp + 7) & ~(uintptr_t)7);
    uint2* staged   = (uint2*)(rowdeg + N + 8);
    uint_t* csr     = (uint_t*)(staged + (size_t)NB * CAPB);
    (void)ws_size;

    const int ZT = (TI + 255) / 256;
    const int WB = (3 * 32768 + 4096 + 255) / 256;  // 400
    const int XB = (N * 32 + 255) / 256;            // 6250
    const int gB = (E + EPB - 1) / EPB;             // 391
    const int gF = (N + 15) / 16;                   // 3125

    SetupArgs sa;
    sa.Wm0 = Wm[0]; sa.Wu0 = Wu[0];
    sa.Wm1 = Wm[1]; sa.Wu1 = Wu[1];
    sa.Wm2 = Wm[2]; sa.Wu2 = Wu[2];
    sa.Wout = Wout; sa.x = x; sa.ei = ei;
    sa.wswz = wswz; sa.woswz = woswz; sa.xb = xb;
    sa.tails = tails; sa.flag = flag;
    sa.N = N; sa.E = E; sa.TI = TI;
    sa.ZT = ZT; sa.WB = WB; sa.XB = XB;
    setup_kernel<<<ZT + 1 + WB + XB, 256, 0, stream>>>(sa);

    bin_kernel<<<gB, 256, 0, stream>>>(ei, ew, flag, tails, staged, E, NB);
    place_kernel<<<NB, 256, 0, stream>>>(staged, tails, cursor, csr, rowdeg, N);

    fused_layer<0><<<gF, 256, 0, stream>>>(csr, rowdeg, xb, wswz, bu[0], hA,
                                           nullptr, nullptr, nullptr, N);
    fused_layer<0><<<gF, 256, 0, stream>>>(csr, rowdeg, hA, wswz + 32768, bu[1], hB,
                                           nullptr, nullptr, nullptr, N);
    fused_layer<1><<<gF, 256, 0, stream>>>(csr, rowdeg, hB, wswz + 2 * 32768, bu[2],
                                           nullptr, woswz, bout, out, N);
}